// Round 11
// baseline (58.037 us; speedup 1.0000x reference)
//
#include <hip/hip_runtime.h>
#include <hip/hip_bf16.h>

#define Bdim 4096
#define Ldim 4096
#define Hdim 1024
#define BM 128
#define BN 256
#define BK 32
#define NT (Hdim / BK)   // 32 K-tiles

typedef __attribute__((ext_vector_type(8))) __bf16 bf16x8;
typedef __attribute__((ext_vector_type(4))) float floatx4;

__device__ __forceinline__ unsigned short f2bf(float f) {
  union { __hip_bfloat16 h; unsigned short u; } c;
  c.h = __float2bfloat16(f);
  return c.u;
}

// ---- prep (R10 champion version, unchanged): 2048 blocks x 256 thr.
// blocks [0,1024): W->bf16 + bias, one wave per row, pure shfl reduce.
// blocks [1024,2048): X->bf16, 4 float4/thread.
__global__ __launch_bounds__(256) void prep_kernel(
    const float* __restrict__ X, const float* __restrict__ E,
    const float* __restrict__ W, const float* __restrict__ b,
    unsigned short* __restrict__ Xb, unsigned short* __restrict__ Wb,
    float* __restrict__ bias) {
  const int blk = blockIdx.x;
  const int t = threadIdx.x;
  if (blk < 1024) {
    const int wave = t >> 6;
    const int lane = t & 63;
    const int row = blk * 4 + wave;
    const float4* wrow = reinterpret_cast<const float4*>(W + (size_t)row * Hdim);
    const float4* erow = reinterpret_cast<const float4*>(E + (size_t)row * Hdim);
    ushort4* wbrow = reinterpret_cast<ushort4*>(Wb + (size_t)row * Hdim);
    float dot = 0.f;
#pragma unroll
    for (int j = 0; j < 4; ++j) {
      const int idx = lane + j * 64;
      const float4 wv = wrow[idx];
      const float4 ev = erow[idx];
      ushort4 o;
      o.x = f2bf(wv.x); o.y = f2bf(wv.y); o.z = f2bf(wv.z); o.w = f2bf(wv.w);
      wbrow[idx] = o;
      dot += wv.x * ev.x + wv.y * ev.y + wv.z * ev.z + wv.w * ev.w;
    }
#pragma unroll
    for (int off = 32; off > 0; off >>= 1) dot += __shfl_down(dot, off, 64);
    if (lane == 0) bias[row] = dot + b[row];
  } else {
    const int base = (blk - 1024) * 1024 + t;
    const float4* xs = reinterpret_cast<const float4*>(X);
    ushort4* xd = reinterpret_cast<ushort4*>(Xb);
#pragma unroll
    for (int j = 0; j < 4; ++j) {
      const float4 v = xs[base + j * 256];
      ushort4 o;
      o.x = f2bf(v.x); o.y = f2bf(v.y); o.z = f2bf(v.z); o.w = f2bf(v.w);
      xd[base + j * 256] = o;
    }
  }
}

// ---- C[B,L] = Xb @ Wb^T + bias -----------------------------------------
// R11: desync experiment, confounds removed (R6: reg-packing failure;
// R3: weak ring schedule). 128x256 tile, BK=32, 8 waves (2M x 4N, 64x64
// each, acc[4][4]=64 regs, total unified ~120 <= 128), LDS 48 KB ->
// TWO clean blocks/CU (grid 512 = 2x256CU; launch_bounds(512,4) pins
// 4 waves/SIMD). Mechanism: co-resident block fills the SIMDs during
// this block's barrier waits and epilogue/prologue.
// R5's proven 4-phase/tile cadence, 3 GLL/tile (A=1, B=2 half-stages):
//   P0: [stage Bh0(t+1)->o] reads A(0-1)+B(0-1); BAR; lgkm0; 4 MFMA
//   P1: [stage Bh1(t+1)->o] reads A(2-3);        BAR; lgkm0; 4 MFMA; BAR
//   P2: [stage A(t+2)->c  ] reads B(2-3);        BAR; lgkm0; 4 MFMA; BAR
//   P3:                      GATE vmcnt(1)+BAR;               4 MFMA
// WAR: all af reads of c complete at P1's post-MFMA BAR -> A(t+2) into
// c.A at P2 safe; o.B last read at t-1's P2, certified by t-1's P2
// post-MFMA BAR + P3 gate. Gate: at P3 per-wave outstanding =
// {B(t+1)h0, B(t+1)h1, A(t+2)} (A(t+1) retired by prev gate); vmcnt(1)
// retires all of tile t+1's data, leaves A(t+2) in flight. Newest
// retired load (Bh1) issued 2 phases earlier. Tile 30: stages B(31),
// GATE0 (drains A31+B31). Tile 31: no stage/gate. Never vmcnt(0) mid-loop.
// LDS swizzle for 64B rows (4 x 16B slots): stored slot = logical ^
// ((row>>1)&3). Read lanes (fr=lane&15, fq=lane>>4): bank base =
// 16*(fr&1) + 4*(fq^((fr>>1)&3)) -> 8 distinct values over 16 rows =
// uniform 2-way aliasing (free, m136). GLL dest linear; SOURCE
// pre-swizzled: row=tid>>2 -> xor term (tid>>3)&3.
__global__ __launch_bounds__(512, 4) void gemm_bias_kernel(
    const unsigned short* __restrict__ A,   // [Bdim][Hdim] bf16 bits
    const unsigned short* __restrict__ Bw,  // [Ldim][Hdim] bf16 bits
    const float* __restrict__ bias,         // [Ldim]
    float* __restrict__ C) {                // [Bdim][Ldim] fp32
  __shared__ __align__(16) unsigned short ldsA[2][BM * BK];  // 2 x 8 KB
  __shared__ __align__(16) unsigned short ldsB[2][BN * BK];  // 2 x 16 KB

  const int tid = threadIdx.x;
  const int wave = tid >> 6;
  const int lane = tid & 63;
  const int wm = wave >> 2;   // 0..1  (M half, 64 rows)
  const int wn = wave & 3;    // 0..3  (N quarter, 64 cols)
  const int m_blk = blockIdx.y * BM;
  const int n_blk = blockIdx.x * BN;

  // staging source (pre-swizzled): thread covers row tid>>2, 16B-slot tid&3
  const int srow = tid >> 2;                   // 0..127
  const int skofs = ((tid & 3) ^ ((tid >> 3) & 3)) * 8;
  const unsigned short* gA = A + (size_t)(m_blk + srow) * Hdim + skofs;
  const unsigned short* gB = Bw + (size_t)(n_blk + srow) * Hdim + skofs;

  // fragment read offsets (swizzled): row = base+fr, stored slot = fq^((fr>>1)&3)
  const int fr = lane & 15;
  const int fq = lane >> 4;
  const int kx = (fq ^ ((fr >> 1) & 3)) * 8;
  const int aBase = (wm * 64 + fr) * BK;
  const int bBase = (wn * 64 + fr) * BK;

  floatx4 acc[4][4] = {};
  bf16x8 af[4], bfv[4];

#define GLL(src, dst)                                                  \
  __builtin_amdgcn_global_load_lds(                                    \
      (const __attribute__((address_space(1))) void*)(src),            \
      (__attribute__((address_space(3))) void*)(dst), 16, 0, 0)

  // A tile = 8 KB = one 512-thread GLL round; B half (128 rows) likewise.
#define STAGE_A(c, kt) GLL(gA + (size_t)(kt) * BK, &ldsA[c][tid * 8])
#define STAGE_B(c, h, kt)                                              \
  GLL(gB + (size_t)((h) * 128) * Hdim + (size_t)(kt) * BK,             \
      &ldsB[c][(h) * 128 * BK + tid * 8])

#define READ_A(c, lo)                                                  \
  do {                                                                 \
    _Pragma("unroll") for (int mi = (lo); mi < (lo) + 2; ++mi)         \
      af[mi] = *(const bf16x8*)&ldsA[c][aBase + mi * 16 * BK + kx];    \
  } while (0)

#define READ_B(c, lo)                                                  \
  do {                                                                 \
    _Pragma("unroll") for (int ni = (lo); ni < (lo) + 2; ++ni)         \
      bfv[ni] = *(const bf16x8*)&ldsB[c][bBase + ni * 16 * BK + kx];   \
  } while (0)

  // one C-quadrant (2 mi x 2 ni, K=32) = 4 MFMA, setprio-wrapped
#define MFMA_Q(M0, N0)                                                 \
  do {                                                                 \
    __builtin_amdgcn_s_setprio(1);                                     \
    _Pragma("unroll") for (int mi = (M0); mi < (M0) + 2; ++mi)         \
      _Pragma("unroll") for (int ni = (N0); ni < (N0) + 2; ++ni)       \
        acc[mi][ni] = __builtin_amdgcn_mfma_f32_16x16x32_bf16(         \
            af[mi], bfv[ni], acc[mi][ni], 0, 0, 0);                    \
    __builtin_amdgcn_s_setprio(0);                                     \
  } while (0)

#define BAR __builtin_amdgcn_s_barrier()
#define LGKM0 asm volatile("s_waitcnt lgkmcnt(0)" ::: "memory")
#define GATE1 asm volatile("s_waitcnt vmcnt(1)\n\ts_barrier" ::: "memory")
#define GATE0 asm volatile("s_waitcnt vmcnt(0)\n\ts_barrier" ::: "memory")

#define TILE_BODY(c, o, kt, DO_B, DO_A, GATE)                          \
  do {                                                                 \
    /* P0 */                                                           \
    if (DO_B) STAGE_B(o, 0, (kt) + 1);                                 \
    READ_A(c, 0);                                                      \
    READ_B(c, 0);                                                      \
    BAR; LGKM0;                                                        \
    MFMA_Q(0, 0);                                                      \
    /* P1 */                                                           \
    if (DO_B) STAGE_B(o, 1, (kt) + 1);                                 \
    READ_A(c, 2);                                                      \
    BAR; LGKM0;                                                        \
    MFMA_Q(2, 0);                                                      \
    BAR;  /* collective: all af reads of buf c complete -> c.A free */ \
    /* P2 */                                                           \
    if (DO_A) STAGE_A(c, (kt) + 2);                                    \
    READ_B(c, 2);                                                      \
    BAR; LGKM0;                                                        \
    MFMA_Q(0, 2);                                                      \
    BAR;  /* collective: all reads of buf c complete */                \
    /* P3 */                                                           \
    GATE;                                                              \
    MFMA_Q(2, 2);                                                      \
  } while (0)

  // prologue: tile 0 fully (A + B halves) + tile 1 A; gate leaves A(1)
  STAGE_A(0, 0);
  STAGE_B(0, 0, 0);
  STAGE_B(0, 1, 0);
  STAGE_A(1, 1);
  GATE1;

#pragma unroll 1
  for (int t = 0; t < NT - 2; t += 2) {
    TILE_BODY(0, 1, t, 1, 1, GATE1);
    TILE_BODY(1, 0, t + 1, 1, 1, GATE1);
  }
  // tile NT-2 (buf 0): stages B(NT-1)->buf1; no A stage; GATE0 drains
  // A(31)+B(31) (B(31)h1 issued 2 phases earlier).
  TILE_BODY(0, 1, NT - 2, 1, 0, GATE0);
  // tile NT-1 (buf 1): all data resident & retired; no stages, no gate.
  TILE_BODY(1, 0, NT - 1, 0, 0, (void)0);

#undef GLL
#undef STAGE_A
#undef STAGE_B
#undef READ_A
#undef READ_B
#undef MFMA_Q
#undef BAR
#undef LGKM0
#undef GATE1
#undef GATE0
#undef TILE_BODY

  // epilogue: C/D layout col=lane&15, row=(lane>>4)*4+reg  [m89-verified]
  const int col0 = n_blk + wn * 64 + fr;
  const int row0 = m_blk + wm * 64 + fq * 4;
#pragma unroll
  for (int ni = 0; ni < 4; ++ni) {
    const float bs = bias[col0 + ni * 16];
#pragma unroll
    for (int mi = 0; mi < 4; ++mi) {
      float* cp = C + (size_t)(row0 + mi * 16) * Ldim + (col0 + ni * 16);
      floatx4 v = acc[mi][ni];
      cp[0 * (size_t)Ldim] = v.x + bs;
      cp[1 * (size_t)Ldim] = v.y + bs;
      cp[2 * (size_t)Ldim] = v.z + bs;
      cp[3 * (size_t)Ldim] = v.w + bs;
    }
  }
}

extern "C" void kernel_launch(void* const* d_in, const int* in_sizes, int n_in,
                              void* d_out, int out_size, void* d_ws, size_t ws_size,
                              hipStream_t stream) {
  const float* X = (const float*)d_in[0];  // bert_output [B,H]
  const float* E = (const float*)d_in[1];  // label_embed [L,H]
  const float* W = (const float*)d_in[2];  // W [L,H]
  const float* b = (const float*)d_in[3];  // b [L]
  // d_in[4] = labels, unused by the reference output.
  float* out = (float*)d_out;

  unsigned short* Xb = (unsigned short*)d_ws;                 // 8 MB
  unsigned short* Wb = Xb + (size_t)Bdim * Hdim;              // 8 MB
  float* bias = (float*)(Wb + (size_t)Ldim * Hdim);           // 16 KB

  prep_kernel<<<2048, 256, 0, stream>>>(X, E, W, b, Xb, Wb, bias);
  dim3 grid(Ldim / BN, Bdim / BM);
  gemm_bias_kernel<<<grid, 512, 0, stream>>>(Xb, Wb, bias, out);
}

// Round 12
// 49.677 us; speedup vs baseline: 1.1683x; 1.1683x over previous
//
#include <hip/hip_runtime.h>
#include <hip/hip_bf16.h>

#define Bdim 4096
#define Ldim 4096
#define Hdim 1024
#define BM 256
#define BN 256
#define BK 64
#define NT (Hdim / BK)   // 16 K-tiles

typedef __attribute__((ext_vector_type(8))) __bf16 bf16x8;
typedef __attribute__((ext_vector_type(4))) float floatx4;

__device__ __forceinline__ unsigned short f2bf(float f) {
  union { __hip_bfloat16 h; unsigned short u; } c;
  c.h = __float2bfloat16(f);
  return c.u;
}

// ---- prep (R10 champion version, unchanged): 2048 blocks x 256 thr.
// blocks [0,1024): W->bf16 + bias, one wave per row, pure shfl reduce.
// blocks [1024,2048): X->bf16, 4 float4/thread.
__global__ __launch_bounds__(256) void prep_kernel(
    const float* __restrict__ X, const float* __restrict__ E,
    const float* __restrict__ W, const float* __restrict__ b,
    unsigned short* __restrict__ Xb, unsigned short* __restrict__ Wb,
    float* __restrict__ bias) {
  const int blk = blockIdx.x;
  const int t = threadIdx.x;
  if (blk < 1024) {
    const int wave = t >> 6;
    const int lane = t & 63;
    const int row = blk * 4 + wave;
    const float4* wrow = reinterpret_cast<const float4*>(W + (size_t)row * Hdim);
    const float4* erow = reinterpret_cast<const float4*>(E + (size_t)row * Hdim);
    ushort4* wbrow = reinterpret_cast<ushort4*>(Wb + (size_t)row * Hdim);
    float dot = 0.f;
#pragma unroll
    for (int j = 0; j < 4; ++j) {
      const int idx = lane + j * 64;
      const float4 wv = wrow[idx];
      const float4 ev = erow[idx];
      ushort4 o;
      o.x = f2bf(wv.x); o.y = f2bf(wv.y); o.z = f2bf(wv.z); o.w = f2bf(wv.w);
      wbrow[idx] = o;
      dot += wv.x * ev.x + wv.y * ev.y + wv.z * ev.z + wv.w * ev.w;
    }
#pragma unroll
    for (int off = 32; off > 0; off >>= 1) dot += __shfl_down(dot, off, 64);
    if (lane == 0) bias[row] = dot + b[row];
  } else {
    const int base = (blk - 1024) * 1024 + t;
    const float4* xs = reinterpret_cast<const float4*>(X);
    ushort4* xd = reinterpret_cast<ushort4*>(Xb);
#pragma unroll
    for (int j = 0; j < 4; ++j) {
      const float4 v = xs[base + j * 256];
      ushort4 o;
      o.x = f2bf(v.x); o.y = f2bf(v.y); o.z = f2bf(v.z); o.w = f2bf(v.w);
      xd[base + j * 256] = o;
    }
  }
}

// ---- C[B,L] = Xb @ Wb^T + bias -----------------------------------------
// R12 = R10 champion (49.6us) with ONE change: P2's post-MFMA barrier
// removed (6 -> 5 barriers/tile). Redundancy proof: that barrier could
// only certify "all waves' reads of c.B complete" for the NEXT tile's P0
// stage into c.B -- but every wave reaches the P3 gate-BAR only after its
// P2 READ_B+LGKM0 in program order, and the next tile's P0 stage issues
// after the gate-BAR, so the gate already certifies it. (R8's "minimal
// barriers regressed" was confounded by NT stores; this isolates one
// provably-dead barrier.)
// Otherwise byte-identical: 256x256, BK=64, 8 waves (2M x 4N, 128x64
// each), 4-phase/tile cadence:
//   P0: [stage Bh0(t+1)->o] reads A(0-3)+B(0-1); BAR; lgkm0; 16 MFMA
//   P1: [stage Bh1(t+1)->o] reads A(4-7);        BAR; lgkm0; 16 MFMA; BAR
//   P2: [stage Ah0(t+2)->c] reads B(2-3);        BAR; lgkm0; 16 MFMA
//   P3: [stage Ah1(t+2)->c] GATE vmcnt(4)+BAR;               16 MFMA
// WAR: all af reads of c complete at P1's post-MFMA BAR -> A(t+2) into c.A
// at P2/P3 safe; o.B last read at t-1's P2, certified by t-1 P3's gate.
// Gate: at P3 outstanding = A(t+1)[4]+B(t+1)[4]+A(t+2)[4]=12; vmcnt(4)
// retires all of t+1, keeps A(t+2) in flight. Tile 14 stages B(15), GATE0.
// Tile 15: no stage/gate. Never vmcnt(0) mid-loop.
// LDS swizzle (T2, conflicts=0 measured): 16B-slot ks of row r at ks^(r&7);
// GLL dest linear, global SOURCE pre-swizzled, reads same XOR.
__global__ __launch_bounds__(512, 2) void gemm_bias_kernel(
    const unsigned short* __restrict__ A,   // [Bdim][Hdim] bf16 bits
    const unsigned short* __restrict__ Bw,  // [Ldim][Hdim] bf16 bits
    const float* __restrict__ bias,         // [Ldim]
    float* __restrict__ C) {                // [Bdim][Ldim] fp32
  __shared__ __align__(16) unsigned short lds[2][2][BM * BK];  // 128 KB

  const int tid = threadIdx.x;
  const int wave = tid >> 6;
  const int lane = tid & 63;
  const int wm = wave >> 2;   // 0..1  (M half)
  const int wn = wave & 3;    // 0..3  (N quarter)
  const int m_blk = blockIdx.y * BM;
  const int n_blk = blockIdx.x * BN;

  // staging source (pre-swizzled): wave covers rows [wave*8,+8) per GLL
  const int srow = wave * 8 + (lane >> 3);
  const int skofs = ((lane & 7) ^ (lane >> 3)) * 8;
  const unsigned short* gA = A + (size_t)(m_blk + srow) * Hdim + skofs;
  const unsigned short* gB = Bw + (size_t)(n_blk + srow) * Hdim + skofs;

  // fragment read offsets (swizzled): row = base+fr, k 16B-slot = ksl*4+fq
  const int fr = lane & 15;
  const int fq = lane >> 4;
  const int kx0 = ((fq) ^ (fr & 7)) * 8;        // k 0..31
  const int kx1 = ((4 + fq) ^ (fr & 7)) * 8;    // k 32..63
  const int aBase = (wm * 128 + fr) * BK;
  const int bBase = (wn * 64 + fr) * BK;

  floatx4 acc[8][4] = {};
  bf16x8 af[8][2], bfv[4][2];

#define GLL(src, dst)                                                  \
  __builtin_amdgcn_global_load_lds(                                    \
      (const __attribute__((address_space(1))) void*)(src),            \
      (__attribute__((address_space(3))) void*)(dst), 16, 0, 0)

  // stage one half-tile (mat 0=A 1=B, h = row-half) of K-tile kt into buf c
#define STAGE_H(c, mat, h, kt)                                         \
  do {                                                                 \
    const unsigned short* _g = (mat) ? gB : gA;                        \
    GLL(_g + (size_t)((h) * 128) * Hdim + (size_t)(kt) * BK,           \
        &lds[c][mat][((h) * 128 + wave * 8) * BK]);                    \
    GLL(_g + (size_t)((h) * 128 + 64) * Hdim + (size_t)(kt) * BK,      \
        &lds[c][mat][((h) * 128 + 64 + wave * 8) * BK]);               \
  } while (0)

#define READ_A(c, lo)                                                  \
  do {                                                                 \
    _Pragma("unroll") for (int mi = (lo); mi < (lo) + 4; ++mi) {       \
      af[mi][0] = *(const bf16x8*)&lds[c][0][aBase + mi * 16 * BK + kx0]; \
      af[mi][1] = *(const bf16x8*)&lds[c][0][aBase + mi * 16 * BK + kx1]; \
    }                                                                  \
  } while (0)

#define READ_B(c, lo)                                                  \
  do {                                                                 \
    _Pragma("unroll") for (int ni = (lo); ni < (lo) + 2; ++ni) {       \
      bfv[ni][0] = *(const bf16x8*)&lds[c][1][bBase + ni * 16 * BK + kx0]; \
      bfv[ni][1] = *(const bf16x8*)&lds[c][1][bBase + ni * 16 * BK + kx1]; \
    }                                                                  \
  } while (0)

#define MFMA_Q(M0, N0)                                                 \
  do {                                                                 \
    __builtin_amdgcn_s_setprio(1);                                     \
    _Pragma("unroll") for (int mi = (M0); mi < (M0) + 4; ++mi)         \
      _Pragma("unroll") for (int ni = (N0); ni < (N0) + 2; ++ni) {     \
        acc[mi][ni] = __builtin_amdgcn_mfma_f32_16x16x32_bf16(         \
            af[mi][0], bfv[ni][0], acc[mi][ni], 0, 0, 0);              \
        acc[mi][ni] = __builtin_amdgcn_mfma_f32_16x16x32_bf16(         \
            af[mi][1], bfv[ni][1], acc[mi][ni], 0, 0, 0);              \
      }                                                                \
    __builtin_amdgcn_s_setprio(0);                                     \
  } while (0)

#define BAR __builtin_amdgcn_s_barrier()
#define LGKM0 asm volatile("s_waitcnt lgkmcnt(0)" ::: "memory")
#define GATE4 asm volatile("s_waitcnt vmcnt(4)\n\ts_barrier" ::: "memory")
#define GATE0 asm volatile("s_waitcnt vmcnt(0)\n\ts_barrier" ::: "memory")

  // DO_B: stage B(kt+1)->o at P0/P1.  DO_A: stage A(kt+2)->c at P2/P3.
#define TILE_BODY(c, o, kt, DO_B, DO_A, GATE)                          \
  do {                                                                 \
    /* P0 */                                                           \
    if (DO_B) STAGE_H(o, 1, 0, (kt) + 1);                              \
    READ_A(c, 0);                                                      \
    READ_B(c, 0);                                                      \
    BAR; LGKM0;                                                        \
    MFMA_Q(0, 0);                                                      \
    /* P1 */                                                           \
    if (DO_B) STAGE_H(o, 1, 1, (kt) + 1);                              \
    READ_A(c, 4);                                                      \
    BAR; LGKM0;                                                        \
    MFMA_Q(4, 0);                                                      \
    BAR;  /* collective: all af reads of buf c complete -> c.A free */ \
    /* P2 */                                                           \
    if (DO_A) STAGE_H(c, 0, 0, (kt) + 2);                              \
    READ_B(c, 2);                                                      \
    BAR; LGKM0;                                                        \
    MFMA_Q(0, 2);                                                      \
    /* (R12: post-MFMA barrier removed -- P3's gate-BAR certifies all   \
       c.B reads for the next tile's P0 stage; see header proof) */    \
    /* P3 */                                                           \
    if (DO_A) STAGE_H(c, 0, 1, (kt) + 2);                              \
    GATE;                                                              \
    MFMA_Q(4, 2);                                                      \
  } while (0)

  // prologue: tile 0 fully + tile 1 A halves (12 GLLs), gate to 4
  STAGE_H(0, 0, 0, 0);
  STAGE_H(0, 0, 1, 0);
  STAGE_H(0, 1, 0, 0);
  STAGE_H(0, 1, 1, 0);
  STAGE_H(1, 0, 0, 1);
  STAGE_H(1, 0, 1, 1);
  GATE4;

#pragma unroll 1
  for (int t = 0; t < NT - 2; t += 2) {
    TILE_BODY(0, 1, t, 1, 1, GATE4);
    TILE_BODY(1, 0, t + 1, 1, 1, GATE4);
  }
  // tile NT-2 (buf 0): stages B(NT-1)->buf1; no A stage; GATE0 drains
  // A(15)+B(15) (B(15) issued 2 phases earlier).
  TILE_BODY(0, 1, NT - 2, 1, 0, GATE0);
  // tile NT-1 (buf 1): all data resident & retired; no stages, no gate.
  TILE_BODY(1, 0, NT - 1, 0, 0, (void)0);

#undef GLL
#undef STAGE_H
#undef READ_A
#undef READ_B
#undef MFMA_Q
#undef BAR
#undef LGKM0
#undef GATE4
#undef GATE0
#undef TILE_BODY

  // epilogue: C/D layout col=lane&15, row=(lane>>4)*4+reg  [m89-verified]
  const int col0 = n_blk + wn * 64 + fr;
  const int row0 = m_blk + wm * 128 + fq * 4;
#pragma unroll
  for (int ni = 0; ni < 4; ++ni) {
    const float bs = bias[col0 + ni * 16];
#pragma unroll
    for (int mi = 0; mi < 8; ++mi) {
      float* cp = C + (size_t)(row0 + mi * 16) * Ldim + (col0 + ni * 16);
      floatx4 v = acc[mi][ni];
      cp[0 * (size_t)Ldim] = v.x + bs;
      cp[1 * (size_t)Ldim] = v.y + bs;
      cp[2 * (size_t)Ldim] = v.z + bs;
      cp[3 * (size_t)Ldim] = v.w + bs;
    }
  }
}

extern "C" void kernel_launch(void* const* d_in, const int* in_sizes, int n_in,
                              void* d_out, int out_size, void* d_ws, size_t ws_size,
                              hipStream_t stream) {
  const float* X = (const float*)d_in[0];  // bert_output [B,H]
  const float* E = (const float*)d_in[1];  // label_embed [L,H]
  const float* W = (const float*)d_in[2];  // W [L,H]
  const float* b = (const float*)d_in[3];  // b [L]
  // d_in[4] = labels, unused by the reference output.
  float* out = (float*)d_out;

  unsigned short* Xb = (unsigned short*)d_ws;                 // 8 MB
  unsigned short* Wb = Xb + (size_t)Bdim * Hdim;              // 8 MB
  float* bias = (float*)(Wb + (size_t)Ldim * Hdim);           // 16 KB

  prep_kernel<<<2048, 256, 0, stream>>>(X, E, W, b, Xb, Wb, bias);
  dim3 grid(Ldim / BN, Bdim / BM);
  gemm_bias_kernel<<<grid, 512, 0, stream>>>(Xb, Wb, bias, out);
}

// Round 13
// 49.358 us; speedup vs baseline: 1.1758x; 1.0065x over previous
//
#include <hip/hip_runtime.h>
#include <hip/hip_bf16.h>

#define Bdim 4096
#define Ldim 4096
#define Hdim 1024
#define BM 256
#define BN 256
#define BK 64
#define NT (Hdim / BK)   // 16 K-tiles

typedef __attribute__((ext_vector_type(8))) __bf16 bf16x8;
typedef __attribute__((ext_vector_type(4))) float floatx4;

__device__ __forceinline__ unsigned short f2bf(float f) {
  union { __hip_bfloat16 h; unsigned short u; } c;
  c.h = __float2bfloat16(f);
  return c.u;
}

// ---- prep (R10 champion version, unchanged): 2048 blocks x 256 thr.
// blocks [0,1024): W->bf16 + bias, one wave per row, pure shfl reduce.
// blocks [1024,2048): X->bf16, 4 float4/thread.
__global__ __launch_bounds__(256) void prep_kernel(
    const float* __restrict__ X, const float* __restrict__ E,
    const float* __restrict__ W, const float* __restrict__ b,
    unsigned short* __restrict__ Xb, unsigned short* __restrict__ Wb,
    float* __restrict__ bias) {
  const int blk = blockIdx.x;
  const int t = threadIdx.x;
  if (blk < 1024) {
    const int wave = t >> 6;
    const int lane = t & 63;
    const int row = blk * 4 + wave;
    const float4* wrow = reinterpret_cast<const float4*>(W + (size_t)row * Hdim);
    const float4* erow = reinterpret_cast<const float4*>(E + (size_t)row * Hdim);
    ushort4* wbrow = reinterpret_cast<ushort4*>(Wb + (size_t)row * Hdim);
    float dot = 0.f;
#pragma unroll
    for (int j = 0; j < 4; ++j) {
      const int idx = lane + j * 64;
      const float4 wv = wrow[idx];
      const float4 ev = erow[idx];
      ushort4 o;
      o.x = f2bf(wv.x); o.y = f2bf(wv.y); o.z = f2bf(wv.z); o.w = f2bf(wv.w);
      wbrow[idx] = o;
      dot += wv.x * ev.x + wv.y * ev.y + wv.z * ev.z + wv.w * ev.w;
    }
#pragma unroll
    for (int off = 32; off > 0; off >>= 1) dot += __shfl_down(dot, off, 64);
    if (lane == 0) bias[row] = dot + b[row];
  } else {
    const int base = (blk - 1024) * 1024 + t;
    const float4* xs = reinterpret_cast<const float4*>(X);
    ushort4* xd = reinterpret_cast<ushort4*>(Xb);
#pragma unroll
    for (int j = 0; j < 4; ++j) {
      const float4 v = xs[base + j * 256];
      ushort4 o;
      o.x = f2bf(v.x); o.y = f2bf(v.y); o.z = f2bf(v.z); o.w = f2bf(v.w);
      xd[base + j * 256] = o;
    }
  }
}

// ---- C[B,L] = Xb @ Wb^T + bias -----------------------------------------
// R13 = R10 champion (49.6us) with ONE change: the three per-phase
// "s_waitcnt lgkmcnt(0)" asm drains are REMOVED. Rationale: the fragment
// reads are plain compiler-visible loads, so the SIWaitcnt pass inserts
// minimal counted lgkmcnt before each consuming MFMA (m97 asm evidence:
// lgkmcnt(4/3/1/0) fine-grained) -- the first MFMA can issue as soon as
// ITS operands land, and the remaining ds_reads overlap the matrix pipe.
// The manual lgkmcnt(0)+memory-clobber forced ALL 12 reads (~270cyc) to
// drain before ANY MFMA, 64x per block. (Rule #18's hazard applies only
// to inline-asm ds_reads; not the case here.) Barriers all kept (R12
// showed barrier count is neutral); gate/stage stream byte-identical.
// Structure: 256x256, BK=64, 8 waves (2M x 4N, 128x64 each), 4-phase/tile:
//   P0: [stage Bh0(t+1)->o] reads A(0-3)+B(0-1); BAR; 16 MFMA
//   P1: [stage Bh1(t+1)->o] reads A(4-7);        BAR; 16 MFMA; BAR
//   P2: [stage Ah0(t+2)->c] reads B(2-3);        BAR; 16 MFMA; BAR
//   P3: [stage Ah1(t+2)->c] GATE vmcnt(4)+BAR;        16 MFMA
// WAR: all af reads of c retired before P1's post-MFMA BAR (the MFMAs
// consuming them have issued, and waitcnt ordering puts their lgkmcnt
// before the barrier-crossing) -> A(t+2) into c.A at P2/P3 safe; o.B last
// read at t-1's P2, certified by t-1 P3's gate-BAR.
// Gate: at P3 outstanding = A(t+1)[4]+B(t+1)[4]+A(t+2)[4]=12; vmcnt(4)
// retires all of t+1, keeps A(t+2) in flight. Tile 14 stages B(15), GATE0.
// Tile 15: no stage/gate. Never vmcnt(0) mid-loop.
// LDS swizzle (T2, conflicts=0 measured): 16B-slot ks of row r at ks^(r&7);
// GLL dest linear, global SOURCE pre-swizzled, reads same XOR.
__global__ __launch_bounds__(512, 2) void gemm_bias_kernel(
    const unsigned short* __restrict__ A,   // [Bdim][Hdim] bf16 bits
    const unsigned short* __restrict__ Bw,  // [Ldim][Hdim] bf16 bits
    const float* __restrict__ bias,         // [Ldim]
    float* __restrict__ C) {                // [Bdim][Ldim] fp32
  __shared__ __align__(16) unsigned short lds[2][2][BM * BK];  // 128 KB

  const int tid = threadIdx.x;
  const int wave = tid >> 6;
  const int lane = tid & 63;
  const int wm = wave >> 2;   // 0..1  (M half)
  const int wn = wave & 3;    // 0..3  (N quarter)
  const int m_blk = blockIdx.y * BM;
  const int n_blk = blockIdx.x * BN;

  // staging source (pre-swizzled): wave covers rows [wave*8,+8) per GLL
  const int srow = wave * 8 + (lane >> 3);
  const int skofs = ((lane & 7) ^ (lane >> 3)) * 8;
  const unsigned short* gA = A + (size_t)(m_blk + srow) * Hdim + skofs;
  const unsigned short* gB = Bw + (size_t)(n_blk + srow) * Hdim + skofs;

  // fragment read offsets (swizzled): row = base+fr, k 16B-slot = ksl*4+fq
  const int fr = lane & 15;
  const int fq = lane >> 4;
  const int kx0 = ((fq) ^ (fr & 7)) * 8;        // k 0..31
  const int kx1 = ((4 + fq) ^ (fr & 7)) * 8;    // k 32..63
  const int aBase = (wm * 128 + fr) * BK;
  const int bBase = (wn * 64 + fr) * BK;

  floatx4 acc[8][4] = {};
  bf16x8 af[8][2], bfv[4][2];

#define GLL(src, dst)                                                  \
  __builtin_amdgcn_global_load_lds(                                    \
      (const __attribute__((address_space(1))) void*)(src),            \
      (__attribute__((address_space(3))) void*)(dst), 16, 0, 0)

  // stage one half-tile (mat 0=A 1=B, h = row-half) of K-tile kt into buf c
#define STAGE_H(c, mat, h, kt)                                         \
  do {                                                                 \
    const unsigned short* _g = (mat) ? gB : gA;                        \
    GLL(_g + (size_t)((h) * 128) * Hdim + (size_t)(kt) * BK,           \
        &lds[c][mat][((h) * 128 + wave * 8) * BK]);                    \
    GLL(_g + (size_t)((h) * 128 + 64) * Hdim + (size_t)(kt) * BK,      \
        &lds[c][mat][((h) * 128 + 64 + wave * 8) * BK]);               \
  } while (0)

#define READ_A(c, lo)                                                  \
  do {                                                                 \
    _Pragma("unroll") for (int mi = (lo); mi < (lo) + 4; ++mi) {       \
      af[mi][0] = *(const bf16x8*)&lds[c][0][aBase + mi * 16 * BK + kx0]; \
      af[mi][1] = *(const bf16x8*)&lds[c][0][aBase + mi * 16 * BK + kx1]; \
    }                                                                  \
  } while (0)

#define READ_B(c, lo)                                                  \
  do {                                                                 \
    _Pragma("unroll") for (int ni = (lo); ni < (lo) + 2; ++ni) {       \
      bfv[ni][0] = *(const bf16x8*)&lds[c][1][bBase + ni * 16 * BK + kx0]; \
      bfv[ni][1] = *(const bf16x8*)&lds[c][1][bBase + ni * 16 * BK + kx1]; \
    }                                                                  \
  } while (0)

#define MFMA_Q(M0, N0)                                                 \
  do {                                                                 \
    __builtin_amdgcn_s_setprio(1);                                     \
    _Pragma("unroll") for (int mi = (M0); mi < (M0) + 4; ++mi)         \
      _Pragma("unroll") for (int ni = (N0); ni < (N0) + 2; ++ni) {     \
        acc[mi][ni] = __builtin_amdgcn_mfma_f32_16x16x32_bf16(         \
            af[mi][0], bfv[ni][0], acc[mi][ni], 0, 0, 0);              \
        acc[mi][ni] = __builtin_amdgcn_mfma_f32_16x16x32_bf16(         \
            af[mi][1], bfv[ni][1], acc[mi][ni], 0, 0, 0);              \
      }                                                                \
    __builtin_amdgcn_s_setprio(0);                                     \
  } while (0)

#define BAR __builtin_amdgcn_s_barrier()
#define GATE4 asm volatile("s_waitcnt vmcnt(4)\n\ts_barrier" ::: "memory")
#define GATE0 asm volatile("s_waitcnt vmcnt(0)\n\ts_barrier" ::: "memory")

  // DO_B: stage B(kt+1)->o at P0/P1.  DO_A: stage A(kt+2)->c at P2/P3.
#define TILE_BODY(c, o, kt, DO_B, DO_A, GATE)                          \
  do {                                                                 \
    /* P0 */                                                           \
    if (DO_B) STAGE_H(o, 1, 0, (kt) + 1);                              \
    READ_A(c, 0);                                                      \
    READ_B(c, 0);                                                      \
    BAR;                                                               \
    MFMA_Q(0, 0);                                                      \
    /* P1 */                                                           \
    if (DO_B) STAGE_H(o, 1, 1, (kt) + 1);                              \
    READ_A(c, 4);                                                      \
    BAR;                                                               \
    MFMA_Q(4, 0);                                                      \
    BAR;  /* collective: all af reads of buf c complete -> c.A free */ \
    /* P2 */                                                           \
    if (DO_A) STAGE_H(c, 0, 0, (kt) + 2);                              \
    READ_B(c, 2);                                                      \
    BAR;                                                               \
    MFMA_Q(0, 2);                                                      \
    BAR;  /* collective: all reads of buf c complete */                \
    /* P3 */                                                           \
    if (DO_A) STAGE_H(c, 0, 1, (kt) + 2);                              \
    GATE;                                                              \
    MFMA_Q(4, 2);                                                      \
  } while (0)

  // prologue: tile 0 fully + tile 1 A halves (12 GLLs), gate to 4
  STAGE_H(0, 0, 0, 0);
  STAGE_H(0, 0, 1, 0);
  STAGE_H(0, 1, 0, 0);
  STAGE_H(0, 1, 1, 0);
  STAGE_H(1, 0, 0, 1);
  STAGE_H(1, 0, 1, 1);
  GATE4;

#pragma unroll 1
  for (int t = 0; t < NT - 2; t += 2) {
    TILE_BODY(0, 1, t, 1, 1, GATE4);
    TILE_BODY(1, 0, t + 1, 1, 1, GATE4);
  }
  // tile NT-2 (buf 0): stages B(NT-1)->buf1; no A stage; GATE0 drains
  // A(15)+B(15) (B(15) issued 2 phases earlier).
  TILE_BODY(0, 1, NT - 2, 1, 0, GATE0);
  // tile NT-1 (buf 1): all data resident & retired; no stages, no gate.
  TILE_BODY(1, 0, NT - 1, 0, 0, (void)0);

#undef GLL
#undef STAGE_H
#undef READ_A
#undef READ_B
#undef MFMA_Q
#undef BAR
#undef GATE4
#undef GATE0
#undef TILE_BODY

  // epilogue: C/D layout col=lane&15, row=(lane>>4)*4+reg  [m89-verified]
  const int col0 = n_blk + wn * 64 + fr;
  const int row0 = m_blk + wm * 128 + fq * 4;
#pragma unroll
  for (int ni = 0; ni < 4; ++ni) {
    const float bs = bias[col0 + ni * 16];
#pragma unroll
    for (int mi = 0; mi < 8; ++mi) {
      float* cp = C + (size_t)(row0 + mi * 16) * Ldim + (col0 + ni * 16);
      floatx4 v = acc[mi][ni];
      cp[0 * (size_t)Ldim] = v.x + bs;
      cp[1 * (size_t)Ldim] = v.y + bs;
      cp[2 * (size_t)Ldim] = v.z + bs;
      cp[3 * (size_t)Ldim] = v.w + bs;
    }
  }
}

extern "C" void kernel_launch(void* const* d_in, const int* in_sizes, int n_in,
                              void* d_out, int out_size, void* d_ws, size_t ws_size,
                              hipStream_t stream) {
  const float* X = (const float*)d_in[0];  // bert_output [B,H]
  const float* E = (const float*)d_in[1];  // label_embed [L,H]
  const float* W = (const float*)d_in[2];  // W [L,H]
  const float* b = (const float*)d_in[3];  // b [L]
  // d_in[4] = labels, unused by the reference output.
  float* out = (float*)d_out;

  unsigned short* Xb = (unsigned short*)d_ws;                 // 8 MB
  unsigned short* Wb = Xb + (size_t)Bdim * Hdim;              // 8 MB
  float* bias = (float*)(Wb + (size_t)Ldim * Hdim);           // 16 KB

  prep_kernel<<<2048, 256, 0, stream>>>(X, E, W, b, Xb, Wb, bias);
  dim3 grid(Ldim / BN, Bdim / BM);
  gemm_bias_kernel<<<grid, 512, 0, stream>>>(Xb, Wb, bias, out);
}